// Round 2
// baseline (400.651 us; speedup 1.0000x reference)
//
#include <hip/hip_runtime.h>
#include <math.h>

// SGRUCell T=32 B=8 I=512 H=512, all f32.
// Persistent kernel: block (q=blk>>3, b=blk&7) owns rows i in [16q,16q+16) of
// batch b; 16 waves, one row per wave. Cross-block h exchange:
//   producer: each wave's lane0 agent-stores its row's h into o_outs, then
//   s_waitcnt(0) (store acked at coherence point), then relaxed fetch_add on
//   the block's MONOTONE counter (one 128B-spread line per block, no per-step
//   clearing, no announce barrier).
//   consumer: wave 0 polls the 32 counters (one lane each, NARROW poll -- the
//   R1 experiment showed wide polling floods the fabric and regresses 60%)
//   until all >= 16*t, then waves 0-3 one-shot-read h from global and compute
//   the 4 gates while waves 4-11 one-shot-fill LDS h. Two barriers per step
//   (post-poll, post-fill) vs R0's five.
// te lives in registers (redundant per block, bitwise deterministic across
// blocks since gates/h are identical). sh_h is a 2-slot rotation: slot written
// at step t (post-b1(t)) is read at t and t+1; reads at t+1 finish before
// b1(t+2) < writes(t+2) => race-free with 2 barriers/step. sh_gates single
// buffer: written pre-b2(t), read post-b2(t), next write post-b1(t+1).
// waves_per_eu(4,4): grid=256 blocks = 1 block/CU (16 waves = 4/SIMD); gives
// the allocator the full 128-VGPR budget so the ~80 persistent floats stay in
// arch VGPRs instead of AGPR round-trips (both prior rounds reported 64 VGPRs).

#define ATOMIC_LD(p) __hip_atomic_load((p), __ATOMIC_RELAXED, __HIP_MEMORY_SCOPE_AGENT)
#define ATOMIC_ST(p, v) __hip_atomic_store((p), (v), __ATOMIC_RELAXED, __HIP_MEMORY_SCOPE_AGENT)

__device__ __forceinline__ float wred(float v) {
#pragma unroll
  for (int o = 32; o > 0; o >>= 1) v += __shfl_xor(v, o, 64);
  return v;
}
__device__ __forceinline__ float sigm(float x) { return 1.f / (1.f + __expf(-x)); }

__global__ void prenorm_kernel(const float* __restrict__ xv, const float* __restrict__ xg,
                               const float* __restrict__ hv, const float* __restrict__ hg,
                               float* __restrict__ scx, float* __restrict__ sch,
                               unsigned* __restrict__ flg) {
  int r = blockIdx.x, L = threadIdx.x;
  if (r < 16) {  // clear 256 spread counters (8192 words; ws poisoned pre-launch)
#pragma unroll
    for (int k = 0; k < 8; k++) flg[r * 512 + k * 64 + L] = 0u;
  }
  const float* vrow; const float* g; float* o; int rr;
  if (r < 1536) { rr = r; vrow = xv + (size_t)r * 512; g = xg; o = scx; }
  else { rr = r - 1536; vrow = hv + (size_t)rr * 512; g = hg; o = sch; }
  float s = 0.f;
#pragma unroll
  for (int m = 0; m < 8; m++) { float v = vrow[m * 64 + L]; s = fmaf(v, v, s); }
  s = wred(s);
  if (L == 0) o[rr] = g[rr] / sqrtf(s);
}

__global__ __attribute__((amdgpu_flat_work_group_size(1024, 1024), amdgpu_waves_per_eu(4, 4)))
void persist_kernel(
    const float* __restrict__ x,
    const float* __restrict__ h0, const float* __restrict__ v0,
    const float* __restrict__ dU0, const float* __restrict__ te0,
    const float* __restrict__ tE0,
    const float* __restrict__ x2h_v, const float* __restrict__ x2h_b,
    const float* __restrict__ h2h_v, const float* __restrict__ h2h_b,
    const float* __restrict__ alpha,
    const float* __restrict__ h2mod_w, const float* __restrict__ h2mod_b,
    const float* __restrict__ modU_w, const float* __restrict__ modU_b,
    const float* __restrict__ scx, const float* __restrict__ sch,
    unsigned* __restrict__ flg,
    float* __restrict__ o_v, float* __restrict__ o_h,
    float* __restrict__ o_dU, float* __restrict__ o_te,
    float* __restrict__ o_tE, float* __restrict__ o_outs) {
  __shared__ float sh_h[2][512];       // h 2-slot rotation (4 KB)
  __shared__ float sh_mod[2048];       // h2mod_w 4x512 (8 KB)
  __shared__ float sh_xpz[32][16];     // precomputed x-proj (z) + biases
  __shared__ float sh_xpdv[32][16];    // precomputed x-proj (dv) + biases
  __shared__ float sh_gates[4];        // gate scalars (single-buffered, safe)

  const int tid = threadIdx.x;
  const int w = tid >> 6, L = tid & 63;
  const int b = blockIdx.x & 7, q = blockIdx.x >> 3;
  const int i = q * 16 + w;  // owned row

  if (tid < 512) sh_h[0][tid] = h0[b * 512 + tid];
  sh_mod[tid] = h2mod_w[tid];
  sh_mod[tid + 1024] = h2mod_w[tid + 1024];

  const int rz = i, rdv = 1024 + i, rr = 512 + i;
  const size_t row  = ((size_t)(b * 512 + i)) * 512;
  const size_t wrow = (size_t)i * 512;

  // ---- x-projection precompute FIRST (keeps register pressure low) ----
  {
    float xz[8], xdv[8];
    const float sx_z = scx[rz], sx_dv = scx[rdv];
#pragma unroll
    for (int m = 0; m < 8; m++) {
      int c = m * 64 + L;
      xz[m]  = sx_z  * x2h_v[(size_t)rz  * 512 + c];
      xdv[m] = sx_dv * x2h_v[(size_t)rdv * 512 + c];
    }
    float bz = 0.f, bdv = 0.f;
    if (L == 0) {
      bz  = x2h_b[i] + h2h_b[i];
      bdv = x2h_b[1024 + i] + h2h_b[1024 + i];
    }
#pragma unroll 4
    for (int t = 0; t < 32; t++) {
      const float* xr = x + (size_t)t * 4096 + b * 512;
      float a = 0.f, d = 0.f;
#pragma unroll
      for (int m = 0; m < 8; m++) {
        int c = m * 64 + L;
        float xv_ = xr[c];
        a = fmaf(xz[m], xv_, a);
        d = fmaf(xdv[m], xv_, d);
      }
      a = wred(a); d = wred(d);
      if (L == 0) { sh_xpz[t][w] = a + bz; sh_xpdv[t][w] = d + bdv; }
    }
  }

  // ---- persistent register tables (10x8 = 80 floats) ----
  float wz[8], wdv[8], mw[8], mb[8], al[8], upS[8], loS[8], D[8], tE[8], te[8];
  {
    const float s_z = sch[rz], s_dv = sch[rdv], s_r = sch[rr];
#pragma unroll
    for (int m = 0; m < 8; m++) {
      int c = m * 64 + L;
      wz[m]  = s_z  * h2h_v[(size_t)rz  * 512 + c];
      wdv[m] = s_dv * h2h_v[(size_t)rdv * 512 + c];
      mw[m] = modU_w[wrow + c];
      mb[m] = modU_b[wrow + c];
      float alv = alpha[wrow + c];
      al[m] = alv;
      float wrv = s_r * h2h_v[(size_t)rr * 512 + c];
      float t1 = alv / (alv + 1e-5f);   // alpha * (1/(alpha+eps)), prescaled
      upS[m] = fmaxf(1.f - wrv, 0.f) * t1;
      loS[m] = -fmaxf(1.f + wrv, 0.f) * t1;
      D[m]  = alv * dU0[row + c];       // scaled state: D = alpha * dU
      tE[m] = tE0[row + c];
      te[m] = te0[b * 512 + c];         // eligibility trace, in registers
    }
  }
  float v_reg    = v0[b * 512 + i];     // identical on all lanes
  float h_cur_i  = h0[b * 512 + i];     // h_t[i]   (own row)
  float h_prev_i = 0.f;                 // h_{t-1}[i]; valid from end of t=0
  float te_i     = te0[b * 512 + i];
  float gb = (w < 4) ? h2mod_b[w] : 0.f;
  __syncthreads();

  unsigned* hxu = (unsigned*)o_outs;              // h exchange via output buffer
  unsigned* ctr = flg + (b * 32 + q) * 32;        // this block's monotone counter
  int cur = 0;                                    // sh_h slot holding carry h_t

  for (int t = 0; t <= 32; ++t) {
    const int prevslot = cur;
    if (t > 0) {
      cur ^= 1;
      // ---- narrow poll: wave 0, one counter per lane, 32 spread lines ----
      if (w == 0) {
        const unsigned* fp = flg + (b * 32 + (L & 31)) * 32;
        const unsigned target = (unsigned)(t << 4);   // 16 waves * t steps
        unsigned u;
        do { u = ATOMIC_LD(fp); } while (!__all(u >= target));
      }
      __syncthreads();  // b1: h_t guaranteed globally visible past this point
      const unsigned* hsrc = hxu + (size_t)(t - 1) * 4096 + b * 512;
      if (w < 4) {
        // gates: one-shot global read (no retry), dot with sh_mod row w
        float gp = 0.f;
#pragma unroll
        for (int m = 0; m < 8; m++) {
          unsigned u = ATOMIC_LD(hsrc + m * 64 + L);
          gp = fmaf(__uint_as_float(u), sh_mod[w * 512 + m * 64 + L], gp);
        }
        gp = wred(gp);
        if (L == 0) { gp += gb; sh_gates[w] = (w == 3) ? fmaxf(gp, 0.f) : sigm(gp); }
      } else if (w < 12) {
        // LDS fill: one-shot, one word per thread
        const int j = tid - 256;
        sh_h[cur][j] = __uint_as_float(ATOMIC_LD(hsrc + j));
      }
      __syncthreads();  // b2: gates + sh_h[cur] ready
    }

    float p1 = 0.f, p2 = 0.f;
    if (t > 0) {
      const float taue = sh_gates[0], tauE = sh_gates[1];
      const float tauU = sh_gates[2], mU   = sh_gates[3];
      te_i += taue * (h_prev_i - te_i);
#pragma unroll
      for (int m = 0; m < 8; m++) {
        int c = m * 64 + L;
        float hcm = sh_h[cur][c];        // h_t
        float hpm = sh_h[prevslot][c];   // h_{t-1}
        te[m] += taue * (hpm - te[m]);
        float outer = h_cur_i * te[m] - te_i * hcm;
        tE[m] += tauE * (outer - tE[m]);
        float a = fmaf(mU, mw[m], mb[m]);
        float sshr = (a > 0.5f) ? (a - 0.5f) : ((a < -0.5f) ? (a + 0.5f) : 0.f);
        float Dn = D[m] + tauU * (sshr * (al[m] * tE[m]) - D[m]);
        D[m] = fminf(fmaxf(Dn, loS[m]), upS[m]);
        p1 = fmaf(wz[m], hcm, p1);
        p2 = fmaf(wdv[m] + D[m], hcm, p2);
      }
    } else {
#pragma unroll
      for (int m = 0; m < 8; m++) {
        float hcm = sh_h[0][m * 64 + L];
        p1 = fmaf(wz[m], hcm, p1);
        p2 = fmaf(wdv[m] + D[m], hcm, p2);
      }
    }

    if (t < 32) {
      p1 = wred(p1); p2 = wred(p2);
      float z  = sigm(p1 + sh_xpz[t][w]);
      float dv = p2 + sh_xpdv[t][w];
      v_reg += z * (dv - v_reg);
      float hn = fmaxf(v_reg, 0.f);
      if (L == 0)
        ATOMIC_ST(hxu + (size_t)t * 4096 + b * 512 + i, __float_as_uint(hn));
      __builtin_amdgcn_s_waitcnt(0);     // per-wave: own store acked at agent scope
      if (L == 0)
        __hip_atomic_fetch_add(ctr, 1u, __ATOMIC_RELAXED, __HIP_MEMORY_SCOPE_AGENT);
      h_prev_i = h_cur_i;
      h_cur_i  = hn;
    }
  }

  // ---- final writes (registers only, no barrier needed) ----
#pragma unroll
  for (int m = 0; m < 8; m++) {
    int c = m * 64 + L;
    float alv = al[m];
    o_dU[row + c] = (alv != 0.f) ? D[m] * __builtin_amdgcn_rcpf(alv) : 0.f;
    o_tE[row + c] = tE[m];
  }
  if (L == 0) { o_v[b * 512 + i] = v_reg; o_h[b * 512 + i] = h_cur_i; }
  if (q == 0 && w == 0) {
#pragma unroll
    for (int m = 0; m < 8; m++) o_te[b * 512 + m * 64 + L] = te[m];
  }
}

extern "C" void kernel_launch(void* const* d_in, const int* in_sizes, int n_in,
                              void* d_out, int out_size, void* d_ws, size_t ws_size,
                              hipStream_t stream) {
  const float* x       = (const float*)d_in[0];
  const float* h0      = (const float*)d_in[1];
  const float* v0      = (const float*)d_in[2];
  const float* dU0     = (const float*)d_in[3];
  const float* te0     = (const float*)d_in[4];
  const float* tE0     = (const float*)d_in[5];
  const float* x2h_v   = (const float*)d_in[6];
  const float* x2h_g   = (const float*)d_in[7];
  const float* x2h_b   = (const float*)d_in[8];
  const float* h2h_v   = (const float*)d_in[9];
  const float* h2h_g   = (const float*)d_in[10];
  const float* h2h_b   = (const float*)d_in[11];
  const float* alpha   = (const float*)d_in[12];
  const float* h2mod_w = (const float*)d_in[13];
  const float* h2mod_b = (const float*)d_in[14];
  const float* modU_w  = (const float*)d_in[15];
  const float* modU_b  = (const float*)d_in[16];

  float* out = (float*)d_out;
  // output layout: v(4096) h(4096) dU(2097152) te(4096) tE(2097152) outs(131072)
  float* o_v    = out;
  float* o_h    = out + 4096;
  float* o_dU   = out + 8192;
  float* o_te   = out + 2105344;
  float* o_tE   = out + 2109440;
  float* o_outs = out + 4206592;

  unsigned* flg = (unsigned*)d_ws;           // 256 counters spread 128B (32 KB)
  float* wsf = (float*)d_ws;
  float* scx = wsf + 8192;                   // 1536
  float* sch = wsf + 9728;                   // 1536

  prenorm_kernel<<<dim3(3072), dim3(64), 0, stream>>>(x2h_v, x2h_g, h2h_v, h2h_g,
                                                      scx, sch, flg);

  persist_kernel<<<dim3(256), dim3(1024), 0, stream>>>(
      x, h0, v0, dU0, te0, tE0, x2h_v, x2h_b, h2h_v, h2h_b, alpha,
      h2mod_w, h2mod_b, modU_w, modU_b, scx, sch, flg,
      o_v, o_h, o_dU, o_te, o_tE, o_outs);
}

// Round 3
// 299.170 us; speedup vs baseline: 1.3392x; 1.3392x over previous
//
#include <hip/hip_runtime.h>
#include <math.h>

// SGRUCell T=32 B=8 I=512 H=512, all f32.
// Persistent kernel: block (q=blk>>3, b=blk&7) owns rows i in [16q,16q+16) of
// batch b; 16 waves, one row per wave. ALL per-row tables in registers.
//
// Cross-block h exchange: EXACT R0 mechanism (measured best, 175us):
//   producer: lane0 agent-stores h row -> s_waitcnt(0) (ack) -> barrier ->
//   tid0 stores 1 to a FRESH per-(step,batch,block) flag word (write-once,
//   line quiesces after 32 single stores). consumer: wave 0 ONLY polls the
//   32 packed flags (narrow), then one-shot reads h.
//   Hard-won invariants (R1/R2 regressions): never poll data lines while
//   they are being written (dirty-line coherence storm, +13..+60MB WRITE);
//   never RMW a reused counter line (never quiesces); exactly one spinning
//   wave per block.
//
// R3 delta vs R0 (intra-block only): te lives in registers (deletes the
// te LDS pass + barrier); gates overlap the dot prologue (waves 0-3 each do
// one gate dot from LDS then join loop A; waves 4-15 start loop A at once);
// fused loop B does te/tE/D/p2. Barriers/step: 5 -> 4.
// sh_h 2-slot rotation: slot written at t (b1..b2) read at t and t+1
// (before b3(t+1)); next write at t+2 after b1(t+2) > b3(t+1) => race-free.
// sh_gates single-buffered: written (b2..b2.5) of t, read (b2.5..b3) of t;
// next write after b2(t+1) > b3(t) => safe.

#define ATOMIC_LD(p) __hip_atomic_load((p), __ATOMIC_RELAXED, __HIP_MEMORY_SCOPE_AGENT)
#define ATOMIC_ST(p, v) __hip_atomic_store((p), (v), __ATOMIC_RELAXED, __HIP_MEMORY_SCOPE_AGENT)

__device__ __forceinline__ float wred(float v) {
#pragma unroll
  for (int o = 32; o > 0; o >>= 1) v += __shfl_xor(v, o, 64);
  return v;
}
__device__ __forceinline__ float sigm(float x) { return 1.f / (1.f + __expf(-x)); }

__global__ void prenorm_kernel(const float* __restrict__ xv, const float* __restrict__ xg,
                               const float* __restrict__ hv, const float* __restrict__ hg,
                               float* __restrict__ scx, float* __restrict__ sch,
                               unsigned* __restrict__ flg) {
  int r = blockIdx.x, L = threadIdx.x;
  if (r < 16) {  // clear 32*8*32 arrival flags (ws is poisoned 0xAA pre-launch)
#pragma unroll
    for (int k = 0; k < 8; k++) flg[r * 512 + k * 64 + L] = 0u;
  }
  const float* vrow; const float* g; float* o; int rr;
  if (r < 1536) { rr = r; vrow = xv + (size_t)r * 512; g = xg; o = scx; }
  else { rr = r - 1536; vrow = hv + (size_t)rr * 512; g = hg; o = sch; }
  float s = 0.f;
#pragma unroll
  for (int m = 0; m < 8; m++) { float v = vrow[m * 64 + L]; s = fmaf(v, v, s); }
  s = wred(s);
  if (L == 0) o[rr] = g[rr] / sqrtf(s);
}

__global__ __launch_bounds__(1024, 4) void persist_kernel(
    const float* __restrict__ x,
    const float* __restrict__ h0, const float* __restrict__ v0,
    const float* __restrict__ dU0, const float* __restrict__ te0,
    const float* __restrict__ tE0,
    const float* __restrict__ x2h_v, const float* __restrict__ x2h_b,
    const float* __restrict__ h2h_v, const float* __restrict__ h2h_b,
    const float* __restrict__ alpha,
    const float* __restrict__ h2mod_w, const float* __restrict__ h2mod_b,
    const float* __restrict__ modU_w, const float* __restrict__ modU_b,
    const float* __restrict__ scx, const float* __restrict__ sch,
    unsigned* __restrict__ flg,
    float* __restrict__ o_v, float* __restrict__ o_h,
    float* __restrict__ o_dU, float* __restrict__ o_te,
    float* __restrict__ o_tE, float* __restrict__ o_outs) {
  __shared__ float sh_h[2][512];       // h 2-slot rotation (4 KB)
  __shared__ float sh_mod[2048];       // h2mod_w 4x512 (8 KB)
  __shared__ float sh_xpz[32][16];     // precomputed x-proj (z) + biases
  __shared__ float sh_xpdv[32][16];    // precomputed x-proj (dv) + biases
  __shared__ float sh_gates[4];        // gate scalars (single-buffered, safe)

  const int tid = threadIdx.x;
  const int w = tid >> 6, L = tid & 63;
  const int b = blockIdx.x & 7, q = blockIdx.x >> 3;
  const int i = q * 16 + w;  // owned row

  if (tid < 512) sh_h[0][tid] = h0[b * 512 + tid];
  sh_mod[tid] = h2mod_w[tid];
  sh_mod[tid + 1024] = h2mod_w[tid + 1024];

  const int rz = i, rdv = 1024 + i, rr = 512 + i;
  const size_t row  = ((size_t)(b * 512 + i)) * 512;
  const size_t wrow = (size_t)i * 512;

  // ---- x-projection precompute FIRST (keeps register pressure low) ----
  {
    float xz[8], xdv[8];
    const float sx_z = scx[rz], sx_dv = scx[rdv];
#pragma unroll
    for (int m = 0; m < 8; m++) {
      int c = m * 64 + L;
      xz[m]  = sx_z  * x2h_v[(size_t)rz  * 512 + c];
      xdv[m] = sx_dv * x2h_v[(size_t)rdv * 512 + c];
    }
    float bz = 0.f, bdv = 0.f;
    if (L == 0) {
      bz  = x2h_b[i] + h2h_b[i];
      bdv = x2h_b[1024 + i] + h2h_b[1024 + i];
    }
#pragma unroll 4
    for (int t = 0; t < 32; t++) {
      const float* xr = x + (size_t)t * 4096 + b * 512;
      float a = 0.f, d = 0.f;
#pragma unroll
      for (int m = 0; m < 8; m++) {
        int c = m * 64 + L;
        float xv_ = xr[c];
        a = fmaf(xz[m], xv_, a);
        d = fmaf(xdv[m], xv_, d);
      }
      a = wred(a); d = wred(d);
      if (L == 0) { sh_xpz[t][w] = a + bz; sh_xpdv[t][w] = d + bdv; }
    }
  }

  // ---- persistent register tables (10x8 = 80 floats) ----
  float wz[8], wdv[8], mw[8], mb[8], al[8], upS[8], loS[8], D[8], tE[8], te[8];
  {
    const float s_z = sch[rz], s_dv = sch[rdv], s_r = sch[rr];
#pragma unroll
    for (int m = 0; m < 8; m++) {
      int c = m * 64 + L;
      wz[m]  = s_z  * h2h_v[(size_t)rz  * 512 + c];
      wdv[m] = s_dv * h2h_v[(size_t)rdv * 512 + c];
      mw[m] = modU_w[wrow + c];
      mb[m] = modU_b[wrow + c];
      float alv = alpha[wrow + c];
      al[m] = alv;
      float wrv = s_r * h2h_v[(size_t)rr * 512 + c];
      float t1 = alv / (alv + 1e-5f);   // alpha * (1/(alpha+eps)), prescaled
      upS[m] = fmaxf(1.f - wrv, 0.f) * t1;
      loS[m] = -fmaxf(1.f + wrv, 0.f) * t1;
      D[m]  = alv * dU0[row + c];       // scaled state: D = alpha * dU
      tE[m] = tE0[row + c];
      te[m] = te0[b * 512 + c];         // eligibility trace, in registers
    }
  }
  float v_reg    = v0[b * 512 + i];     // identical on all lanes
  float h_cur_i  = h0[b * 512 + i];     // h_t[i]   (own row)
  float h_prev_i = 0.f;                 // h_{t-1}[i]; valid from end of t=0
  float te_i     = te0[b * 512 + i];
  float gb = (w < 4) ? h2mod_b[w] : 0.f;
  __syncthreads();

  unsigned* hxu = (unsigned*)o_outs;    // h exchanged through the output buffer
  int cur = 0;                          // sh_h slot holding h_t (slot0 = h0)

  for (int t = 0; t <= 32; ++t) {
    const int prevslot = cur;
    if (t > 0) {
      cur ^= 1;
      // ---- narrow poll: wave 0 only, 32 packed flags (R0 mechanism) ----
      if (w == 0) {
        const unsigned* fp = flg + ((t - 1) * 8 + b) * 32 + (L & 31);
        unsigned u;
        do { u = ATOMIC_LD(fp); } while (!__all(u != 0u));
      }
      __syncthreads();  // b1: h_t quiesced at coherence point past this line
      if (tid < 512)    // one-shot read of h_t (data line never polled)
        sh_h[cur][tid] = __uint_as_float(
            ATOMIC_LD(hxu + (size_t)(t - 1) * 4096 + b * 512 + tid));
      __syncthreads();  // b2: sh_h[cur] ready
    }

    float p1 = 0.f, p2 = 0.f;
    float hc[8];
    if (t > 0) {
      // gate wave w (<4) computes gate w, overlapped with others' loop A
      if (w < 4) {
        float gp = 0.f;
#pragma unroll
        for (int m = 0; m < 8; m++) {
          int c = m * 64 + L;
          gp = fmaf(sh_h[cur][c], sh_mod[w * 512 + c], gp);
        }
        gp = wred(gp);
        if (L == 0) { gp += gb; sh_gates[w] = (w == 3) ? fmaxf(gp, 0.f) : sigm(gp); }
      }
      // loop A: everyone loads h_t to regs and accumulates p1
#pragma unroll
      for (int m = 0; m < 8; m++) {
        int c = m * 64 + L;
        hc[m] = sh_h[cur][c];
        p1 = fmaf(wz[m], hc[m], p1);
      }
      p1 = wred(p1);      // overlap the shuffle tree with the gate window
      __syncthreads();    // b2.5: sh_gates ready
      const float taue = sh_gates[0], tauE = sh_gates[1];
      const float tauU = sh_gates[2], mU   = sh_gates[3];
      te_i += taue * (h_prev_i - te_i);
      // loop B: fused te/tE/D update + p2 (pure reg + 8 LDS reads)
#pragma unroll
      for (int m = 0; m < 8; m++) {
        int c = m * 64 + L;
        float hpm = sh_h[prevslot][c];   // h_{t-1}
        te[m] += taue * (hpm - te[m]);
        float outer = h_cur_i * te[m] - te_i * hc[m];
        tE[m] += tauE * (outer - tE[m]);
        float a = fmaf(mU, mw[m], mb[m]);
        float sshr = (a > 0.5f) ? (a - 0.5f) : ((a < -0.5f) ? (a + 0.5f) : 0.f);
        float Dn = D[m] + tauU * (sshr * (al[m] * tE[m]) - D[m]);
        D[m] = fminf(fmaxf(Dn, loS[m]), upS[m]);
        p2 = fmaf(wdv[m] + D[m], hc[m], p2);
      }
    } else {
#pragma unroll
      for (int m = 0; m < 8; m++) {
        float hcm = sh_h[0][m * 64 + L];
        p1 = fmaf(wz[m], hcm, p1);
        p2 = fmaf(wdv[m] + D[m], hcm, p2);
      }
      p1 = wred(p1);
    }

    if (t < 32) {
      p2 = wred(p2);
      float z  = sigm(p1 + sh_xpz[t][w]);
      float dv = p2 + sh_xpdv[t][w];
      v_reg += z * (dv - v_reg);
      float hn = fmaxf(v_reg, 0.f);
      if (L == 0)
        ATOMIC_ST(hxu + (size_t)t * 4096 + b * 512 + i, __float_as_uint(hn));
      __builtin_amdgcn_s_waitcnt(0);  // own h store acked at coherence point
      __syncthreads();                 // b3: all 16 rows acked
      if (tid == 0)
        ATOMIC_ST(flg + (t * 8 + b) * 32 + q, 1u);  // write-once flag
      h_prev_i = h_cur_i;
      h_cur_i  = hn;
    }
  }

  // ---- final writes (register-only; no barrier needed) ----
#pragma unroll
  for (int m = 0; m < 8; m++) {
    int c = m * 64 + L;
    float alv = al[m];
    o_dU[row + c] = (alv != 0.f) ? D[m] * __builtin_amdgcn_rcpf(alv) : 0.f;
    o_tE[row + c] = tE[m];
  }
  if (L == 0) { o_v[b * 512 + i] = v_reg; o_h[b * 512 + i] = h_cur_i; }
  if (q == 0 && w == 0) {  // wave 0 holds the full te vector in registers
#pragma unroll
    for (int m = 0; m < 8; m++) o_te[b * 512 + m * 64 + L] = te[m];
  }
}

extern "C" void kernel_launch(void* const* d_in, const int* in_sizes, int n_in,
                              void* d_out, int out_size, void* d_ws, size_t ws_size,
                              hipStream_t stream) {
  const float* x       = (const float*)d_in[0];
  const float* h0      = (const float*)d_in[1];
  const float* v0      = (const float*)d_in[2];
  const float* dU0     = (const float*)d_in[3];
  const float* te0     = (const float*)d_in[4];
  const float* tE0     = (const float*)d_in[5];
  const float* x2h_v   = (const float*)d_in[6];
  const float* x2h_g   = (const float*)d_in[7];
  const float* x2h_b   = (const float*)d_in[8];
  const float* h2h_v   = (const float*)d_in[9];
  const float* h2h_g   = (const float*)d_in[10];
  const float* h2h_b   = (const float*)d_in[11];
  const float* alpha   = (const float*)d_in[12];
  const float* h2mod_w = (const float*)d_in[13];
  const float* h2mod_b = (const float*)d_in[14];
  const float* modU_w  = (const float*)d_in[15];
  const float* modU_b  = (const float*)d_in[16];

  float* out = (float*)d_out;
  // output layout: v(4096) h(4096) dU(2097152) te(4096) tE(2097152) outs(131072)
  float* o_v    = out;
  float* o_h    = out + 4096;
  float* o_dU   = out + 8192;
  float* o_te   = out + 2105344;
  float* o_tE   = out + 2109440;
  float* o_outs = out + 4206592;

  unsigned* flg = (unsigned*)d_ws;           // 32*8*32 arrival flags (32 KB)
  float* wsf = (float*)d_ws;
  float* scx = wsf + 8192;                   // 1536
  float* sch = wsf + 9728;                   // 1536

  prenorm_kernel<<<dim3(3072), dim3(64), 0, stream>>>(x2h_v, x2h_g, h2h_v, h2h_g,
                                                      scx, sch, flg);

  persist_kernel<<<dim3(256), dim3(1024), 0, stream>>>(
      x, h0, v0, dU0, te0, tE0, x2h_v, x2h_b, h2h_v, h2h_b, alpha,
      h2mod_w, h2mod_b, modU_w, modU_b, scx, sch, flg,
      o_v, o_h, o_dU, o_te, o_tE, o_outs);
}

// Round 4
// 238.861 us; speedup vs baseline: 1.6773x; 1.2525x over previous
//
#include <hip/hip_runtime.h>
#include <math.h>

// SGRUCell T=32 B=8 I=512 H=512, all f32.
// Persistent kernel: block (q=blk>>3, b=blk&7) owns rows i in [16q,16q+16) of
// batch b; 16 waves, one row per wave. Body is the R0 champion (175us) byte-
// for-byte: 5 barrier-delimited phases, te in LDS, 72 persistent regs/lane.
//
// R4 delta: exchange only. R0's chain was store(sc1)->waitcnt ACK->barrier->
// flag store->consumer poll->read (ack + flag propagation + read = ~3 RTT).
// Now: lane0 of each wave drops hn into an LDS gather (the existing producer
// barrier orders it, and with only plain stores outstanding its implicit
// vmcnt drain is local-L2 cheap); then wave 15 issues ONE 16-lane contiguous
// 64B store of SIGN-TAGGED values (hn>=0 => sign bit free) to a write-once
// workspace line. Consumers: wave 0 polls 32 tag words (narrow, R0-style);
// the 512-wide one-shot read verifies each word's tag (retry ~never taken,
// correct even if the 64B transaction split). Data arrival = one-way
// propagation; no ack, no flag, no fence on the critical path.
// Hard-won invariants kept (R1/R2): narrow poll only; write-once lines that
// quiesce; no RMW flags; never wide-poll in-flight data (the verify loop is
// post-coarse-poll, expected 1 iteration).
// Exchange store on wave 15 (not in tid<512): its sc1 ack drains at the next
// barrier while wave 0 polls -- off the critical path.

#define ATOMIC_LD(p) __hip_atomic_load((p), __ATOMIC_RELAXED, __HIP_MEMORY_SCOPE_AGENT)
#define ATOMIC_ST(p, v) __hip_atomic_store((p), (v), __ATOMIC_RELAXED, __HIP_MEMORY_SCOPE_AGENT)

__device__ __forceinline__ float wred(float v) {
#pragma unroll
  for (int o = 32; o > 0; o >>= 1) v += __shfl_xor(v, o, 64);
  return v;
}
__device__ __forceinline__ float sigm(float x) { return 1.f / (1.f + __expf(-x)); }

__global__ void prenorm_kernel(const float* __restrict__ xv, const float* __restrict__ xg,
                               const float* __restrict__ hv, const float* __restrict__ hg,
                               float* __restrict__ scx, float* __restrict__ sch,
                               unsigned* __restrict__ exch) {
  int r = blockIdx.x, L = threadIdx.x;
  // exch is poisoned 0xAA (sign bit SET = would look ready): clear 131072
  // words (512KB). 2048 blocks x 64 threads x 1 word.
  if (r < 2048) exch[r * 64 + L] = 0u;
  const float* vrow; const float* g; float* o; int rr;
  if (r < 1536) { rr = r; vrow = xv + (size_t)r * 512; g = xg; o = scx; }
  else { rr = r - 1536; vrow = hv + (size_t)rr * 512; g = hg; o = sch; }
  float s = 0.f;
#pragma unroll
  for (int m = 0; m < 8; m++) { float v = vrow[m * 64 + L]; s = fmaf(v, v, s); }
  s = wred(s);
  if (L == 0) o[rr] = g[rr] / sqrtf(s);
}

__global__ __launch_bounds__(1024, 4) void persist_kernel(
    const float* __restrict__ x,
    const float* __restrict__ h0, const float* __restrict__ v0,
    const float* __restrict__ dU0, const float* __restrict__ te0,
    const float* __restrict__ tE0,
    const float* __restrict__ x2h_v, const float* __restrict__ x2h_b,
    const float* __restrict__ h2h_v, const float* __restrict__ h2h_b,
    const float* __restrict__ alpha,
    const float* __restrict__ h2mod_w, const float* __restrict__ h2mod_b,
    const float* __restrict__ modU_w, const float* __restrict__ modU_b,
    const float* __restrict__ scx, const float* __restrict__ sch,
    unsigned* __restrict__ exch,
    float* __restrict__ o_v, float* __restrict__ o_h,
    float* __restrict__ o_dU, float* __restrict__ o_te,
    float* __restrict__ o_tE, float* __restrict__ o_outs) {
  __shared__ float sh_hbuf[2][512];   // h ping-pong: buf[t&1] = h_t
  __shared__ float sh_te[512];        // eligibility trace
  __shared__ float sh_mod[2048];      // h2mod_w (4x512)
  __shared__ float sh_xpz[32][16];    // precomputed x-proj (z) + bias, [t][w]
  __shared__ float sh_xpdv[32][16];   // precomputed x-proj (dv) + bias
  __shared__ float sh_gates[4];       // tau_e, tau_E, tau_U, mU
  __shared__ float sh_gather[16];     // per-wave hn gather for the 64B store

  const int tid = threadIdx.x;
  const int w = tid >> 6, L = tid & 63;
  const int b = blockIdx.x & 7, q = blockIdx.x >> 3;
  const int i = q * 16 + w;  // owned row

  // ---- basic LDS staging ----
  if (tid < 512) {
    sh_hbuf[0][tid] = h0[b * 512 + tid];
    sh_te[tid] = te0[b * 512 + tid];
  }
  sh_mod[tid] = h2mod_w[tid];
  sh_mod[tid + 1024] = h2mod_w[tid + 1024];

  const int rz = i, rdv = 1024 + i, rr = 512 + i;
  const size_t row  = ((size_t)(b * 512 + i)) * 512;
  const size_t wrow = (size_t)i * 512;

  // ---- x-projection precompute FIRST (keeps register pressure low) ----
  {
    float xz[8], xdv[8];
    const float sx_z = scx[rz], sx_dv = scx[rdv];
#pragma unroll
    for (int m = 0; m < 8; m++) {
      int c = m * 64 + L;
      xz[m]  = sx_z  * x2h_v[(size_t)rz  * 512 + c];
      xdv[m] = sx_dv * x2h_v[(size_t)rdv * 512 + c];
    }
    float bz = 0.f, bdv = 0.f;
    if (L == 0) {
      bz  = x2h_b[i] + h2h_b[i];
      bdv = x2h_b[1024 + i] + h2h_b[1024 + i];
    }
#pragma unroll 4
    for (int t = 0; t < 32; t++) {
      const float* xr = x + (size_t)t * 4096 + b * 512;
      float a = 0.f, d = 0.f;
#pragma unroll
      for (int m = 0; m < 8; m++) {
        int c = m * 64 + L;
        float xv_ = xr[c];
        a = fmaf(xz[m], xv_, a);
        d = fmaf(xdv[m], xv_, d);
      }
      a = wred(a); d = wred(d);
      if (L == 0) { sh_xpz[t][w] = a + bz; sh_xpdv[t][w] = d + bdv; }
    }
  }

  // ---- persistent register tables (9x8 = 72 floats, as R0) ----
  float wz[8], wdv[8], mw[8], mb[8], al[8], upS[8], loS[8], D[8], tE[8];
  {
    const float s_z = sch[rz], s_dv = sch[rdv], s_r = sch[rr];
#pragma unroll
    for (int m = 0; m < 8; m++) {
      int c = m * 64 + L;
      wz[m]  = s_z  * h2h_v[(size_t)rz  * 512 + c];
      wdv[m] = s_dv * h2h_v[(size_t)rdv * 512 + c];
      mw[m] = modU_w[wrow + c];
      mb[m] = modU_b[wrow + c];
      float alv = alpha[wrow + c];
      al[m] = alv;
      float wrv = s_r * h2h_v[(size_t)rr * 512 + c];
      float t1 = alv / (alv + 1e-5f);   // alpha * (1/(alpha+eps)), prescaled
      upS[m] = fmaxf(1.f - wrv, 0.f) * t1;
      loS[m] = -fmaxf(1.f + wrv, 0.f) * t1;
      float dui = dU0[row + c];
      D[m]  = alv * dui;                // scaled state: D = alpha * dU
      tE[m] = tE0[row + c];
    }
  }
  float v_reg = 0.f, hn_last = 0.f, gb = 0.f;
  if (L == 0) {
    v_reg = v0[b * 512 + i];
    if (w < 4) gb = h2mod_b[w];
  }
  __syncthreads();

  for (int t = 0; t <= 32; t++) {
    const int cur = t & 1, prev = cur ^ 1;
    if (t > 0) {
      const unsigned* eb = exch + ((t - 1) * 8 + b) * 512;
      // ---- arrival: wave 0 polls 32 tag words (one per producer line) ----
      if (w == 0) {
        const unsigned* fp = eb + (L & 31) * 16 + (L & 15);
        unsigned u;
        do {
          u = ATOMIC_LD(fp);
        } while (!__all(u >> 31));
      }
      __syncthreads();
      if (tid < 512) {  // one-shot read of h_t, per-word tag verify (~never loops)
        unsigned u = ATOMIC_LD(eb + tid);
        while (!(u >> 31)) u = ATOMIC_LD(eb + tid);
        sh_hbuf[cur][tid] = __uint_as_float(u & 0x7fffffffu);
      }
      __syncthreads();
      // gates: mod = h_t @ h2mod_w.T + b, waves 0..3
      if (w < 4) {
        float p = 0.f;
        const float* mr = sh_mod + w * 512;
#pragma unroll
        for (int m = 0; m < 8; m++) {
          int c = m * 64 + L;
          p = fmaf(sh_hbuf[cur][c], mr[c], p);
        }
        p = wred(p);
        if (L == 0) {
          p += gb;
          sh_gates[w] = (w == 3) ? fmaxf(p, 0.f) : sigm(p);
        }
      }
      __syncthreads();
      // te_n = te + tau_e*(h_{t-1} - te)
      float taue = sh_gates[0];
      if (tid < 512) sh_te[tid] += taue * (sh_hbuf[prev][tid] - sh_te[tid]);
      __syncthreads();
      // tE / D register update (pure VALU, no global loads)
      float tauE = sh_gates[1], tauU = sh_gates[2], mU = sh_gates[3];
      float hn_i = sh_hbuf[cur][i], te_i = sh_te[i];
#pragma unroll
      for (int m = 0; m < 8; m++) {
        int j = m * 64 + L;
        float outer = hn_i * sh_te[j] - te_i * sh_hbuf[cur][j];
        float tEn = tE[m] + tauE * (outer - tE[m]);
        float a = fmaf(mU, mw[m], mb[m]);
        float sshr = (a > 0.5f) ? (a - 0.5f) : ((a < -0.5f) ? (a + 0.5f) : 0.f);
        float Dn = D[m] + tauU * (sshr * (al[m] * tEn) - D[m]);
        D[m] = fminf(fmaxf(Dn, loS[m]), upS[m]);
        tE[m] = tEn;
      }
    }

    if (t < 32) {
      // z/dv dots for step t (x-part precomputed; D = alpha*dU directly)
      float p1 = 0.f, p2 = 0.f;
#pragma unroll
      for (int m = 0; m < 8; m++) {
        int c = m * 64 + L;
        float hc = sh_hbuf[cur][c];
        p1 = fmaf(wz[m], hc, p1);
        p2 = fmaf(wdv[m] + D[m], hc, p2);
      }
      p1 = wred(p1); p2 = wred(p2);
      if (L == 0) {
        float z = sigm(p1 + sh_xpz[t][w]);
        float dv = p2 + sh_xpdv[t][w];
        v_reg += z * (dv - v_reg);
        hn_last = fmaxf(v_reg, 0.f);
        o_outs[(size_t)t * 4096 + b * 512 + i] = hn_last;  // clean copy, fire&forget
        sh_gather[w] = hn_last;                            // LDS gather for exchange
      }
      __syncthreads();  // orders the gather; only plain stores outstanding (cheap)
      if (w == 15 && L < 16) {
        // ONE 16-lane contiguous 64B tagged store: data is its own flag.
        unsigned u = __float_as_uint(sh_gather[L]) | 0x80000000u;
        ATOMIC_ST(exch + (t * 8 + b) * 512 + q * 16 + L, u);
      }
    }
  }

  // ---- final writes ----
#pragma unroll
  for (int m = 0; m < 8; m++) {
    int c = m * 64 + L;
    float alv = al[m];
    o_dU[row + c] = (alv != 0.f) ? D[m] * __builtin_amdgcn_rcpf(alv) : 0.f;
    o_tE[row + c] = tE[m];
  }
  if (L == 0) {
    o_v[b * 512 + i] = v_reg;
    o_h[b * 512 + i] = hn_last;
  }
  if (q == 0 && tid < 512) o_te[b * 512 + tid] = sh_te[tid];
}

extern "C" void kernel_launch(void* const* d_in, const int* in_sizes, int n_in,
                              void* d_out, int out_size, void* d_ws, size_t ws_size,
                              hipStream_t stream) {
  const float* x       = (const float*)d_in[0];
  const float* h0      = (const float*)d_in[1];
  const float* v0      = (const float*)d_in[2];
  const float* dU0     = (const float*)d_in[3];
  const float* te0     = (const float*)d_in[4];
  const float* tE0     = (const float*)d_in[5];
  const float* x2h_v   = (const float*)d_in[6];
  const float* x2h_g   = (const float*)d_in[7];
  const float* x2h_b   = (const float*)d_in[8];
  const float* h2h_v   = (const float*)d_in[9];
  const float* h2h_g   = (const float*)d_in[10];
  const float* h2h_b   = (const float*)d_in[11];
  const float* alpha   = (const float*)d_in[12];
  const float* h2mod_w = (const float*)d_in[13];
  const float* h2mod_b = (const float*)d_in[14];
  const float* modU_w  = (const float*)d_in[15];
  const float* modU_b  = (const float*)d_in[16];

  float* out = (float*)d_out;
  // output layout: v(4096) h(4096) dU(2097152) te(4096) tE(2097152) outs(131072)
  float* o_v    = out;
  float* o_h    = out + 4096;
  float* o_dU   = out + 8192;
  float* o_te   = out + 2105344;
  float* o_tE   = out + 2109440;
  float* o_outs = out + 4206592;

  float* wsf = (float*)d_ws;
  float* scx = wsf + 8192;                    // 1536 floats
  float* sch = wsf + 9728;                    // 1536 floats
  unsigned* exch = (unsigned*)d_ws + 12288;   // 32*8*32 lines x 16 words = 512KB

  prenorm_kernel<<<dim3(3072), dim3(64), 0, stream>>>(x2h_v, x2h_g, h2h_v, h2h_g,
                                                      scx, sch, exch);

  persist_kernel<<<dim3(256), dim3(1024), 0, stream>>>(
      x, h0, v0, dU0, te0, tE0, x2h_v, x2h_b, h2h_v, h2h_b, alpha,
      h2mod_w, h2mod_b, modU_w, modU_b, scx, sch, exch,
      o_v, o_h, o_dU, o_te, o_tE, o_outs);
}